// Round 6
// baseline (214.783 us; speedup 1.0000x reference)
//
#include <hip/hip_runtime.h>
#include <hip/hip_bf16.h>
#include <stdint.h>

// B=4, S=2048, HDIM=1024, H=16, D=64, L=128, NB=16
// GEMMs: M = B*S = 8192, N = H*D = 1024, K = HDIM = 1024
constexpr int GM = 8192;
constexpr int GK = 1024;
constexpr int GN = 1024;
constexpr size_t NACT = (size_t)GM * GN;      // 8388608 elements
constexpr int CHUNK = 32;                      // scan chunk length
constexpr int NCHUNK = 64;                     // 64*32 = 2048 = S
constexpr int NCH = 4096;                      // B*H*D channels
constexpr int NT = GK / 64;                    // 16 K-tiles of 64

#define DEVINL __device__ __forceinline__

typedef __attribute__((ext_vector_type(8))) short bf16x8;
typedef __attribute__((ext_vector_type(4))) float f32x4;

DEVINL float sigmoidf_(float x) { return 1.0f / (1.0f + __expf(-x)); }

DEVINL unsigned short f2bf(float x) {
  unsigned int u = __builtin_bit_cast(unsigned int, x);
  unsigned int rnd = 0x7fffu + ((u >> 16) & 1u);
  return (unsigned short)((u + rnd) >> 16);
}
DEVINL float bf2f(unsigned short u) {
  unsigned int x = ((unsigned int)u) << 16;
  return __builtin_bit_cast(float, x);
}

DEVINL void gload16(const void* g, void* l) {
  __builtin_amdgcn_global_load_lds(
      (const __attribute__((address_space(1))) unsigned int*)g,
      (__attribute__((address_space(3))) unsigned int*)l, 16, 0, 0);
}

// ---------------- prep: f32 -> bf16 convert, 4 arrays in one dispatch ----------------
__global__ void cvt4_kernel(const float* __restrict__ s0, const float* __restrict__ s1,
                            const float* __restrict__ s2, const float* __restrict__ s3,
                            unsigned short* __restrict__ d0, unsigned short* __restrict__ d1,
                            unsigned short* __restrict__ d2, unsigned short* __restrict__ d3,
                            int n4) {
  const float* s;
  unsigned short* d;
  switch (blockIdx.y) {
    case 0: s = s0; d = d0; break;
    case 1: s = s1; d = d1; break;
    case 2: s = s2; d = d2; break;
    default: s = s3; d = d3; break;
  }
  int stride = gridDim.x * blockDim.x;
  for (int i = blockIdx.x * blockDim.x + threadIdx.x; i < n4; i += stride) {
    float4 v = ((const float4*)s)[i];
    ushort4 o;
    o.x = f2bf(v.x); o.y = f2bf(v.y); o.z = f2bf(v.z); o.w = f2bf(v.w);
    ((ushort4*)d)[i] = o;
  }
}

// ---------------- prep: transpose+cvt all 5 weights in one dispatch ----------------
struct TPtrs {
  const float* src[5];
  unsigned short* dst[5];
};

__global__ void transpose_cvt_all(TPtrs p) {
  const float* __restrict__ W = p.src[blockIdx.z];
  unsigned short* __restrict__ Wt = p.dst[blockIdx.z];
  __shared__ float tile[32][33];
  int n0 = blockIdx.x * 32, k0 = blockIdx.y * 32;
  int tx = threadIdx.x & 31, ty = threadIdx.x >> 5;  // 32x8
#pragma unroll
  for (int i = 0; i < 32; i += 8)
    tile[ty + i][tx] = W[(size_t)(k0 + ty + i) * GN + n0 + tx];
  __syncthreads();
#pragma unroll
  for (int i = 0; i < 32; i += 8)
    Wt[(size_t)(n0 + ty + i) * GK + k0 + tx] = f2bf(tile[tx][ty + i]);
}

// =====================================================================
// 256x256 tile, BK=64, 8 waves (2M x 4N), m201-template 4-phase schedule.
// Residency invariant: at the start of tile t, buf[cur] is globally
// resident (guaranteed by previous tile's P4 {vmcnt(0); barrier}), so each
// phase's ds_reads may be issued BEFORE that phase's barrier and overlap
// the rendezvous / other waves' MFMA.
//  P1: reads q1(12); stage A(t+1); bar; lgkm0; MFMA (mlo,nlo); bar
//  P2: reads bF-hi(4); stage B(t+1); bar; lgkm0; MFMA (mlo,nhi); bar
//  P3: reads aF-hi(8); bar; lgkm0; MFMA (mhi,nhi); bar
//  P4: MFMA (mhi,nlo) [regs only]; vmcnt(0) (issued 3 phases ago ~ free); bar
// LDS 128 KiB: 2 dbuf x (A 32K + B 32K), linear dest + inverse-XOR-swizzled
// global source; reads apply the same XOR involution: cb ^= (row&7)<<4.
// =====================================================================
DEVINL void gemm256_core(const unsigned short* __restrict__ A,
                         const unsigned short* __restrict__ W,
                         char* lds, int tid, int wave, int lane,
                         int bm, int bn, f32x4 (&acc)[8][4]) {
  const int Ah = wave >> 2;        // A half this wave computes (0/1)
  const int wn = (wave & 3) * 64;  // wave's B col offset
  const int lrow = lane & 15;
  const int lgrp = lane >> 4;      // 0..3

  // precompute the 8 per-thread staging (src, dst) pairs; src advances 128 B/tile
  const char* gsrc[8];
  char* ldst[8];
  {
    const char* Ag = (const char*)A;
    const char* Wg = (const char*)W;
#pragma unroll
    for (int hh = 0; hh < 4; ++hh)
#pragma unroll
      for (int j = 0; j < 2; ++j) {
        const int lbyte = j * 8192 + tid * 16;             // linear LDS byte
        const int row = lbyte >> 7;                        // 128 B per row
        const int gcb = (lbyte & 127) ^ ((row & 7) << 4);  // inverse swizzle
        const int i = hh * 2 + j;
        gsrc[i] = (hh < 2)
            ? Ag + (size_t)(bm * 256 + hh * 128 + row) * 2048 + gcb
            : Wg + (size_t)(bn * 256 + (hh - 2) * 128 + row) * 2048 + gcb;
        ldst[i] = lds + (hh >= 2 ? 32768 : 0) + (hh & 1) * 16384 + j * 8192 +
                  wave * 1024;  // HW adds lane*16
      }
  }

  // prologue: tile 0 -> buf 0 (all 8); make globally resident
#pragma unroll
  for (int i = 0; i < 8; ++i) gload16(gsrc[i], ldst[i]);
  asm volatile("s_waitcnt vmcnt(0)" ::: "memory");
  __builtin_amdgcn_s_barrier();

  bf16x8 aF[4][2], bF[4][2];

  for (int t = 0; t < NT; ++t) {
    const int cur = t & 1;
    const int obuf = (cur ^ 1) * 65536;
    const char* Abase = lds + cur * 65536 + Ah * 16384;
    const char* Bbase = lds + cur * 65536 + 32768;
    const int nk = (t + 1 < NT) ? (t + 1) : (NT - 1);  // clamped dummy on last tile
    const size_t koff = (size_t)nk * 128;

    // ---- P1: reads q1; stage A(t+1); bar; lgkm0; MFMA (mlo,nlo); bar ----
#pragma unroll
    for (int m = 0; m < 4; ++m)
#pragma unroll
      for (int ks = 0; ks < 2; ++ks) {
        const int r = m * 16 + lrow;
        const int cb = ks * 64 + lgrp * 16;
        aF[m][ks] = *(const bf16x8*)(Abase + r * 128 + (cb ^ ((r & 7) << 4)));
      }
#pragma unroll
    for (int n = 0; n < 2; ++n)
#pragma unroll
      for (int ks = 0; ks < 2; ++ks) {
        const int nr = wn + n * 16 + lrow;
        const int cb = ks * 64 + lgrp * 16;
        bF[n][ks] = *(const bf16x8*)(Bbase + nr * 128 + (cb ^ ((nr & 7) << 4)));
      }
#pragma unroll
    for (int i = 0; i < 4; ++i) gload16(gsrc[i] + koff, ldst[i] + obuf);
    __builtin_amdgcn_sched_barrier(0);
    __builtin_amdgcn_s_barrier();
    asm volatile("s_waitcnt lgkmcnt(0)" ::: "memory");
    __builtin_amdgcn_sched_barrier(0);
    __builtin_amdgcn_s_setprio(1);
#pragma unroll
    for (int m = 0; m < 4; ++m)
#pragma unroll
      for (int n = 0; n < 2; ++n)
#pragma unroll
        for (int ks = 0; ks < 2; ++ks)
          acc[m][n] = __builtin_amdgcn_mfma_f32_16x16x32_bf16(aF[m][ks], bF[n][ks],
                                                              acc[m][n], 0, 0, 0);
    __builtin_amdgcn_s_setprio(0);
    __builtin_amdgcn_s_barrier();

    // ---- P2: reads bF-hi; stage B(t+1); bar; lgkm0; MFMA (mlo,nhi); bar ----
#pragma unroll
    for (int n = 2; n < 4; ++n)
#pragma unroll
      for (int ks = 0; ks < 2; ++ks) {
        const int nr = wn + n * 16 + lrow;
        const int cb = ks * 64 + lgrp * 16;
        bF[n][ks] = *(const bf16x8*)(Bbase + nr * 128 + (cb ^ ((nr & 7) << 4)));
      }
#pragma unroll
    for (int i = 4; i < 8; ++i) gload16(gsrc[i] + koff, ldst[i] + obuf);
    __builtin_amdgcn_sched_barrier(0);
    __builtin_amdgcn_s_barrier();
    asm volatile("s_waitcnt lgkmcnt(0)" ::: "memory");
    __builtin_amdgcn_sched_barrier(0);
    __builtin_amdgcn_s_setprio(1);
#pragma unroll
    for (int m = 0; m < 4; ++m)
#pragma unroll
      for (int n = 2; n < 4; ++n)
#pragma unroll
        for (int ks = 0; ks < 2; ++ks)
          acc[m][n] = __builtin_amdgcn_mfma_f32_16x16x32_bf16(aF[m][ks], bF[n][ks],
                                                              acc[m][n], 0, 0, 0);
    __builtin_amdgcn_s_setprio(0);
    __builtin_amdgcn_s_barrier();

    // ---- P3: reads aF-hi; bar; lgkm0; MFMA (mhi,nhi); bar ----
#pragma unroll
    for (int m = 0; m < 4; ++m)
#pragma unroll
      for (int ks = 0; ks < 2; ++ks) {
        const int r = (m + 4) * 16 + lrow;
        const int cb = ks * 64 + lgrp * 16;
        aF[m][ks] = *(const bf16x8*)(Abase + r * 128 + (cb ^ ((r & 7) << 4)));
      }
    __builtin_amdgcn_sched_barrier(0);
    __builtin_amdgcn_s_barrier();
    asm volatile("s_waitcnt lgkmcnt(0)" ::: "memory");
    __builtin_amdgcn_sched_barrier(0);
    __builtin_amdgcn_s_setprio(1);
#pragma unroll
    for (int m = 0; m < 4; ++m)
#pragma unroll
      for (int n = 2; n < 4; ++n)
#pragma unroll
        for (int ks = 0; ks < 2; ++ks)
          acc[m + 4][n] = __builtin_amdgcn_mfma_f32_16x16x32_bf16(aF[m][ks], bF[n][ks],
                                                                  acc[m + 4][n], 0, 0, 0);
    __builtin_amdgcn_s_setprio(0);
    __builtin_amdgcn_s_barrier();

    // ---- P4: MFMA (mhi,nlo) regs-only; then make tile t+1 resident ----
    __builtin_amdgcn_s_setprio(1);
#pragma unroll
    for (int m = 0; m < 4; ++m)
#pragma unroll
      for (int n = 0; n < 2; ++n)
#pragma unroll
        for (int ks = 0; ks < 2; ++ks)
          acc[m + 4][n] = __builtin_amdgcn_mfma_f32_16x16x32_bf16(aF[m][ks], bF[n][ks],
                                                                  acc[m + 4][n], 0, 0, 0);
    __builtin_amdgcn_s_setprio(0);
    asm volatile("s_waitcnt vmcnt(0)" ::: "memory");  // issued ~3 phases ago
    __builtin_amdgcn_sched_barrier(0);
    __builtin_amdgcn_s_barrier();
  }
}

// ---------------- batched gate GEMM: z = {f, o, i_raw, z_raw} ----------------
struct GateArgs {
  const unsigned short* A[4];
  const unsigned short* W[4];
  const float* bias[4];
  unsigned short* out[4];
};

__global__ __launch_bounds__(512, 2) void gemm_gates8(GateArgs ga) {
  extern __shared__ char lds[];
  const int tid = threadIdx.x;
  const int wave = tid >> 6, lane = tid & 63;
  const int bm = blockIdx.x, bn = blockIdx.y, gz = blockIdx.z;
  const int wm = (wave >> 2) * 128, wn = (wave & 3) * 64;
  const int lrow = lane & 15, lgrp = lane >> 4;

  f32x4 acc[8][4];
#pragma unroll
  for (int m = 0; m < 8; ++m)
#pragma unroll
    for (int n = 0; n < 4; ++n) acc[m][n] = (f32x4){0.f, 0.f, 0.f, 0.f};

  gemm256_core(ga.A[gz], ga.W[gz], lds, tid, wave, lane, bm, bn, acc);

  const float* bias = ga.bias[gz];
  unsigned short* out = ga.out[gz];
  float bv[4];
#pragma unroll
  for (int n = 0; n < 4; ++n) bv[n] = bias[bn * 256 + wn + n * 16 + lrow];

#pragma unroll
  for (int m = 0; m < 8; ++m)
#pragma unroll
    for (int n = 0; n < 4; ++n) {
      const int gc = bn * 256 + wn + n * 16 + lrow;
#pragma unroll
      for (int j = 0; j < 4; ++j) {
        const int gr = bm * 256 + wm + m * 16 + lgrp * 4 + j;
        float v = acc[m][n][j] + bv[n];
        if (gz == 0) v = sigmoidf_(v + 1.0f);       // f gate
        else if (gz == 1) v = sigmoidf_(v);         // o gate
        // gz==2 (i) / gz==3 (z): raw pre-activation (bias included)
        out[(size_t)gr * GN + gc] = f2bf(v);
      }
    }
}

// ---------------- output projection: bf16 A (Hb), f32 out ----------------
__global__ __launch_bounds__(512, 2) void gemm_proj8(
    const unsigned short* __restrict__ A, const unsigned short* __restrict__ W,
    const float* __restrict__ bias, float* __restrict__ out) {
  extern __shared__ char lds[];
  const int tid = threadIdx.x;
  const int wave = tid >> 6, lane = tid & 63;
  const int bm = blockIdx.x, bn = blockIdx.y;
  const int wm = (wave >> 2) * 128, wn = (wave & 3) * 64;
  const int lrow = lane & 15, lgrp = lane >> 4;

  f32x4 acc[8][4];
#pragma unroll
  for (int m = 0; m < 8; ++m)
#pragma unroll
    for (int n = 0; n < 4; ++n) acc[m][n] = (f32x4){0.f, 0.f, 0.f, 0.f};

  gemm256_core(A, W, lds, tid, wave, lane, bm, bn, acc);

  float bv[4];
#pragma unroll
  for (int n = 0; n < 4; ++n) bv[n] = bias[bn * 256 + wn + n * 16 + lrow];

#pragma unroll
  for (int m = 0; m < 8; ++m)
#pragma unroll
    for (int n = 0; n < 4; ++n) {
      const int gc = bn * 256 + wn + n * 16 + lrow;
#pragma unroll
      for (int j = 0; j < 4; ++j) {
        const int gr = bm * 256 + wm + m * 16 + lgrp * 4 + j;
        out[(size_t)gr * GN + gc] = acc[m][n][j] + bv[n];
      }
    }
}

// ---------------- scan phase A: per-chunk (prod f, local c) ----------------
__global__ void scan_phaseA_kernel(const unsigned short* __restrict__ F,
                                   const unsigned short* __restrict__ Ip,
                                   const unsigned short* __restrict__ Zp,
                                   float* __restrict__ Pt, float* __restrict__ Ct) {
  int tid = blockIdx.x * blockDim.x + threadIdx.x;  // NCH * NCHUNK = 262144
  int ch = tid & (NCH - 1), chunk = tid >> 12;
  int b = ch >> 10, n = ch & 1023;
  size_t base = ((size_t)(b * 2048 + chunk * CHUNK)) * 1024 + n;
  float c = 0.f, P = 1.f;
#pragma unroll 8
  for (int t = 0; t < CHUNK; ++t) {
    size_t idx = base + (size_t)t * 1024;
    float f = bf2f(F[idx]);
    float u = sigmoidf_(bf2f(Ip[idx])) * tanhf(bf2f(Zp[idx]));
    c = __builtin_fmaf(f, c, u);
    P *= f;
  }
  Pt[tid] = P;
  Ct[tid] = c;
}

// ---------------- scan combine: sequential over 64 chunks ----------------
__global__ void scan_combine_kernel(const float* __restrict__ Pt,
                                    const float* __restrict__ Ct,
                                    const float* __restrict__ c0,
                                    float* __restrict__ Cin,
                                    float* __restrict__ last_c) {
  int ch = blockIdx.x * blockDim.x + threadIdx.x;  // 4096
  float c = c0[ch];
#pragma unroll
  for (int j = 0; j < NCHUNK; ++j) {
    Cin[j * NCH + ch] = c;
    c = __builtin_fmaf(Pt[j * NCH + ch], c, Ct[j * NCH + ch]);
  }
  last_c[ch] = c;
}

// ---------------- scan phase C: replay with carry, emit h ----------------
__global__ void scan_phaseC_kernel(const unsigned short* __restrict__ F,
                                   const unsigned short* __restrict__ Ip,
                                   const unsigned short* __restrict__ Zp,
                                   const unsigned short* __restrict__ O,
                                   const float* __restrict__ Cin,
                                   unsigned short* __restrict__ Hb,
                                   float* __restrict__ last_h) {
  int tid = blockIdx.x * blockDim.x + threadIdx.x;
  int ch = tid & (NCH - 1), chunk = tid >> 12;
  int b = ch >> 10, n = ch & 1023;
  size_t base = ((size_t)(b * 2048 + chunk * CHUNK)) * 1024 + n;
  float c = Cin[tid];  // tid == chunk*NCH + ch
  float h = 0.f;
#pragma unroll 8
  for (int t = 0; t < CHUNK; ++t) {
    size_t idx = base + (size_t)t * 1024;
    float f = bf2f(F[idx]);
    float u = sigmoidf_(bf2f(Ip[idx])) * tanhf(bf2f(Zp[idx]));
    float o = bf2f(O[idx]);
    c = __builtin_fmaf(f, c, u);
    h = o * tanhf(c);
    Hb[idx] = f2bf(h);
  }
  if (chunk == NCHUNK - 1) last_h[ch] = h;
}

extern "C" void kernel_launch(void* const* d_in, const int* in_sizes, int n_in,
                              void* d_out, int out_size, void* d_ws, size_t ws_size,
                              hipStream_t stream) {
  const float* f_in = (const float*)d_in[0];
  const float* i_in = (const float*)d_in[1];
  const float* z_in = (const float*)d_in[2];
  const float* o_in = (const float*)d_in[3];
  const float* c0 = (const float*)d_in[4];
  // d_in[5] = h0 (unused by reference)
  const float* Wf = (const float*)d_in[6];
  const float* bf_ = (const float*)d_in[7];
  const float* Wi = (const float*)d_in[8];
  const float* bi = (const float*)d_in[9];
  const float* Wz = (const float*)d_in[10];
  const float* bz = (const float*)d_in[11];
  const float* Wo = (const float*)d_in[12];
  const float* bo = (const float*)d_in[13];
  const float* Wp = (const float*)d_in[14];
  const float* bp = (const float*)d_in[15];

  float* y = (float*)d_out;
  float* last_c = y + NACT;
  float* last_h = last_c + NCH;

  // workspace carve (Hb aliases Af, which is dead after gate GEMMs)
  char* w = (char*)d_ws;
  const size_t ABYTES = NACT * 2;             // 16 MiB
  const size_t WBYTES = (size_t)GK * GN * 2;  // 2 MiB
  unsigned short* Af = (unsigned short*)(w + 0 * ABYTES);
  unsigned short* Ai = (unsigned short*)(w + 1 * ABYTES);
  unsigned short* Az = (unsigned short*)(w + 2 * ABYTES);
  unsigned short* Ao = (unsigned short*)(w + 3 * ABYTES);
  char* wt = w + 4 * ABYTES;
  unsigned short* Wtf = (unsigned short*)(wt + 0 * WBYTES);
  unsigned short* Wti = (unsigned short*)(wt + 1 * WBYTES);
  unsigned short* Wtz = (unsigned short*)(wt + 2 * WBYTES);
  unsigned short* Wto = (unsigned short*)(wt + 3 * WBYTES);
  unsigned short* Wtp = (unsigned short*)(wt + 4 * WBYTES);
  char* gp = wt + 5 * WBYTES;
  unsigned short* F = (unsigned short*)(gp + 0 * ABYTES);
  unsigned short* O = (unsigned short*)(gp + 1 * ABYTES);
  unsigned short* Ip = (unsigned short*)(gp + 2 * ABYTES);
  unsigned short* Zp = (unsigned short*)(gp + 3 * ABYTES);
  unsigned short* Hb = Af;  // alias: Af no longer needed after gate GEMMs
  char* sp = gp + 4 * ABYTES;
  const size_t SBYTES = (size_t)NCH * NCHUNK * 4;  // 1 MiB
  float* Pt = (float*)(sp + 0 * SBYTES);
  float* Ct = (float*)(sp + 1 * SBYTES);
  float* Cin = (float*)(sp + 2 * SBYTES);

  // allow 128 KiB dynamic LDS for the GEMM kernels (idempotent, capture-safe)
  (void)hipFuncSetAttribute((const void*)gemm_gates8,
                            hipFuncAttributeMaxDynamicSharedMemorySize, 131072);
  (void)hipFuncSetAttribute((const void*)gemm_proj8,
                            hipFuncAttributeMaxDynamicSharedMemorySize, 131072);

  // 1) convert activations f32 -> bf16 (one dispatch)
  cvt4_kernel<<<dim3(1024, 4), 256, 0, stream>>>(
      f_in, o_in, i_in, z_in, Af, Ao, Ai, Az, (int)(NACT / 4));

  // 2) transpose+convert weights -> Wt[n][k] bf16 (one dispatch)
  TPtrs tp;
  tp.src[0] = Wf; tp.src[1] = Wi; tp.src[2] = Wz; tp.src[3] = Wo; tp.src[4] = Wp;
  tp.dst[0] = Wtf; tp.dst[1] = Wti; tp.dst[2] = Wtz; tp.dst[3] = Wto; tp.dst[4] = Wtp;
  transpose_cvt_all<<<dim3(32, 32, 5), 256, 0, stream>>>(tp);

  // 3) all 4 gate GEMMs in one dispatch (512 blocks = 2 full CU rounds)
  GateArgs ga;
  ga.A[0] = Af;  ga.A[1] = Ao;  ga.A[2] = Ai;  ga.A[3] = Az;
  ga.W[0] = Wtf; ga.W[1] = Wto; ga.W[2] = Wti; ga.W[3] = Wtz;
  ga.bias[0] = bf_; ga.bias[1] = bo; ga.bias[2] = bi; ga.bias[3] = bz;
  ga.out[0] = F; ga.out[1] = O; ga.out[2] = Ip; ga.out[3] = Zp;
  gemm_gates8<<<dim3(GM / 256, GN / 256, 4), 512, 131072, stream>>>(ga);

  // 4) chunked linear-recurrence scan (u = sigmoid(ip)*tanh(zp) computed in-scan)
  scan_phaseA_kernel<<<(NCH * NCHUNK) / 256, 256, 0, stream>>>(F, Ip, Zp, Pt, Ct);
  scan_combine_kernel<<<NCH / 256, 256, 0, stream>>>(Pt, Ct, c0, Cin, last_c);
  scan_phaseC_kernel<<<(NCH * NCHUNK) / 256, 256, 0, stream>>>(F, Ip, Zp, O, Cin, Hb,
                                                               last_h);

  // 5) output projection
  gemm_proj8<<<dim3(GM / 256, GN / 256), 512, 131072, stream>>>(Hb, Wtp, bp, y);
}

// Round 7
// 211.020 us; speedup vs baseline: 1.0178x; 1.0178x over previous
//
#include <hip/hip_runtime.h>
#include <hip/hip_bf16.h>
#include <stdint.h>

// B=4, S=2048, HDIM=1024, H=16, D=64, L=128, NB=16
// GEMMs: M = B*S = 8192, N = H*D = 1024, K = HDIM = 1024
constexpr int GM = 8192;
constexpr int GK = 1024;
constexpr int GN = 1024;
constexpr size_t NACT = (size_t)GM * GN;      // 8388608 elements
constexpr int CHUNK = 32;                      // scan chunk length
constexpr int NCHUNK = 64;                     // 64*32 = 2048 = S
constexpr int NCH = 4096;                      // B*H*D channels
constexpr int NT = GK / 64;                    // 16 K-tiles of 64

#define DEVINL __device__ __forceinline__

typedef __attribute__((ext_vector_type(8))) short bf16x8;
typedef __attribute__((ext_vector_type(4))) float f32x4;

DEVINL float sigmoidf_(float x) { return 1.0f / (1.0f + __expf(-x)); }

DEVINL unsigned short f2bf(float x) {
  unsigned int u = __builtin_bit_cast(unsigned int, x);
  unsigned int rnd = 0x7fffu + ((u >> 16) & 1u);
  return (unsigned short)((u + rnd) >> 16);
}
DEVINL float bf2f(unsigned short u) {
  unsigned int x = ((unsigned int)u) << 16;
  return __builtin_bit_cast(float, x);
}

DEVINL void gload16(const void* g, void* l) {
  __builtin_amdgcn_global_load_lds(
      (const __attribute__((address_space(1))) unsigned int*)g,
      (__attribute__((address_space(3))) unsigned int*)l, 16, 0, 0);
}

#define SB() __builtin_amdgcn_sched_barrier(0)

// ---------------- prep: f32 -> bf16 convert, 4 arrays in one dispatch ----------------
__global__ void cvt4_kernel(const float* __restrict__ s0, const float* __restrict__ s1,
                            const float* __restrict__ s2, const float* __restrict__ s3,
                            unsigned short* __restrict__ d0, unsigned short* __restrict__ d1,
                            unsigned short* __restrict__ d2, unsigned short* __restrict__ d3,
                            int n4) {
  const float* s;
  unsigned short* d;
  switch (blockIdx.y) {
    case 0: s = s0; d = d0; break;
    case 1: s = s1; d = d1; break;
    case 2: s = s2; d = d2; break;
    default: s = s3; d = d3; break;
  }
  int stride = gridDim.x * blockDim.x;
  for (int i = blockIdx.x * blockDim.x + threadIdx.x; i < n4; i += stride) {
    float4 v = ((const float4*)s)[i];
    ushort4 o;
    o.x = f2bf(v.x); o.y = f2bf(v.y); o.z = f2bf(v.z); o.w = f2bf(v.w);
    ((ushort4*)d)[i] = o;
  }
}

// ---------------- prep: transpose+cvt all 5 weights in one dispatch ----------------
struct TPtrs {
  const float* src[5];
  unsigned short* dst[5];
};

__global__ void transpose_cvt_all(TPtrs p) {
  const float* __restrict__ W = p.src[blockIdx.z];
  unsigned short* __restrict__ Wt = p.dst[blockIdx.z];
  __shared__ float tile[32][33];
  int n0 = blockIdx.x * 32, k0 = blockIdx.y * 32;
  int tx = threadIdx.x & 31, ty = threadIdx.x >> 5;  // 32x8
#pragma unroll
  for (int i = 0; i < 32; i += 8)
    tile[ty + i][tx] = W[(size_t)(k0 + ty + i) * GN + n0 + tx];
  __syncthreads();
#pragma unroll
  for (int i = 0; i < 32; i += 8)
    Wt[(size_t)(n0 + ty + i) * GK + k0 + tx] = f2bf(tile[tx][ty + i]);
}

// =====================================================================
// 256x256 tile, BK=64, 8 waves (2M x 4N). ONE barrier + counted lgkm
// per K-tile (no mid-tile barriers):
//   vmcnt(0)      -- tile t's 8 staging loads (issued during t-1) retired
//   barrier       -- buf[cur] resident for all; all waves done reading obuf
//   stage(t+1)    -- 8 gloads into obuf (no conflict with cur reads)
//   G1 reads(12: aLo+bLo); lgkm(4); G2(4: bHi); lgkm(4); G3(8: aHi)
//   MFMA q1(aLo*bLo); lgkm(8); q2(aLo*bHi); lgkm(0); q3(aHi*bHi)+q4(aHi*bLo)
// Counted waits all <=15 (HW field); max 12 lgkm outstanding. Separate
// aLo/aHi/bLo/bHi reg arrays so early G3 issue can't clobber q1/q2 operands.
// LDS 128 KiB: 2 dbuf x (A 32K + B 32K), linear dest + inverse-XOR-swizzled
// global source; reads apply the same XOR involution: cb ^= (row&7)<<4.
// =====================================================================
DEVINL void gemm256_core(const unsigned short* __restrict__ A,
                         const unsigned short* __restrict__ W,
                         char* lds, int tid, int wave, int lane,
                         int bm, int bn, f32x4 (&acc)[8][4]) {
  const int Ah = wave >> 2;        // A half this wave computes (0/1)
  const int wn = (wave & 3) * 64;  // wave's B col offset
  const int lrow = lane & 15;
  const int lgrp = lane >> 4;      // 0..3

  // precompute the 8 per-thread staging (src, dst) pairs; src advances 128 B/tile
  const char* gsrc[8];
  char* ldst[8];
  {
    const char* Ag = (const char*)A;
    const char* Wg = (const char*)W;
#pragma unroll
    for (int hh = 0; hh < 4; ++hh)
#pragma unroll
      for (int j = 0; j < 2; ++j) {
        const int lbyte = j * 8192 + tid * 16;             // linear LDS byte
        const int row = lbyte >> 7;                        // 128 B per row
        const int gcb = (lbyte & 127) ^ ((row & 7) << 4);  // inverse swizzle
        const int i = hh * 2 + j;
        gsrc[i] = (hh < 2)
            ? Ag + (size_t)(bm * 256 + hh * 128 + row) * 2048 + gcb
            : Wg + (size_t)(bn * 256 + (hh - 2) * 128 + row) * 2048 + gcb;
        ldst[i] = lds + (hh >= 2 ? 32768 : 0) + (hh & 1) * 16384 + j * 8192 +
                  wave * 1024;  // HW adds lane*16
      }
  }

  // prologue: tile 0 -> buf 0 (all 8)
#pragma unroll
  for (int i = 0; i < 8; ++i) gload16(gsrc[i], ldst[i]);

  bf16x8 aLo[4][2], aHi[4][2], bLo[2][2], bHi[2][2];

  for (int t = 0; t < NT; ++t) {
    const int cur = t & 1;
    const int obuf = (cur ^ 1) * 65536;
    const char* Abase = lds + cur * 65536 + Ah * 16384;
    const char* Bbase = lds + cur * 65536 + 32768;
    const int nk = (t + 1 < NT) ? (t + 1) : (NT - 1);  // clamped dummy on last tile
    const size_t koff = (size_t)nk * 128;

    // residency rendezvous (one barrier per K-tile)
    asm volatile("s_waitcnt vmcnt(0)" ::: "memory");
    SB();
    __builtin_amdgcn_s_barrier();
    SB();

    // stage tile t+1 into obuf (issued early; lands during this tile's MFMAs)
#pragma unroll
    for (int i = 0; i < 8; ++i) gload16(gsrc[i] + koff, ldst[i] + obuf);

    // G1: aLo(8) + bLo(4)
#pragma unroll
    for (int m = 0; m < 4; ++m)
#pragma unroll
      for (int ks = 0; ks < 2; ++ks) {
        const int r = m * 16 + lrow;
        const int cb = ks * 64 + lgrp * 16;
        aLo[m][ks] = *(const bf16x8*)(Abase + r * 128 + (cb ^ ((r & 7) << 4)));
      }
#pragma unroll
    for (int n = 0; n < 2; ++n)
#pragma unroll
      for (int ks = 0; ks < 2; ++ks) {
        const int nr = wn + n * 16 + lrow;
        const int cb = ks * 64 + lgrp * 16;
        bLo[n][ks] = *(const bf16x8*)(Bbase + nr * 128 + (cb ^ ((nr & 7) << 4)));
      }
    asm volatile("s_waitcnt lgkmcnt(4)" ::: "memory");
    SB();
    // G2: bHi(4)
#pragma unroll
    for (int n = 0; n < 2; ++n)
#pragma unroll
      for (int ks = 0; ks < 2; ++ks) {
        const int nr = wn + (n + 2) * 16 + lrow;
        const int cb = ks * 64 + lgrp * 16;
        bHi[n][ks] = *(const bf16x8*)(Bbase + nr * 128 + (cb ^ ((nr & 7) << 4)));
      }
    asm volatile("s_waitcnt lgkmcnt(4)" ::: "memory");  // G1 fully done
    SB();
    // G3: aHi(8)
#pragma unroll
    for (int m = 0; m < 4; ++m)
#pragma unroll
      for (int ks = 0; ks < 2; ++ks) {
        const int r = (m + 4) * 16 + lrow;
        const int cb = ks * 64 + lgrp * 16;
        aHi[m][ks] = *(const bf16x8*)(Abase + r * 128 + (cb ^ ((r & 7) << 4)));
      }

    // q1: aLo x bLo (overlaps G2/G3 in flight)
    __builtin_amdgcn_s_setprio(1);
#pragma unroll
    for (int m = 0; m < 4; ++m)
#pragma unroll
      for (int n = 0; n < 2; ++n)
#pragma unroll
        for (int ks = 0; ks < 2; ++ks)
          acc[m][n] = __builtin_amdgcn_mfma_f32_16x16x32_bf16(aLo[m][ks], bLo[n][ks],
                                                              acc[m][n], 0, 0, 0);
    __builtin_amdgcn_s_setprio(0);
    asm volatile("s_waitcnt lgkmcnt(8)" ::: "memory");  // G2 done (G3's 8 remain)
    SB();
    // q2: aLo x bHi
    __builtin_amdgcn_s_setprio(1);
#pragma unroll
    for (int m = 0; m < 4; ++m)
#pragma unroll
      for (int n = 0; n < 2; ++n)
#pragma unroll
        for (int ks = 0; ks < 2; ++ks)
          acc[m][n + 2] = __builtin_amdgcn_mfma_f32_16x16x32_bf16(aLo[m][ks], bHi[n][ks],
                                                                  acc[m][n + 2], 0, 0, 0);
    __builtin_amdgcn_s_setprio(0);
    asm volatile("s_waitcnt lgkmcnt(0)" ::: "memory");  // G3 done
    SB();
    // q3: aHi x bHi ; q4: aHi x bLo -- 32 back-to-back MFMAs
    __builtin_amdgcn_s_setprio(1);
#pragma unroll
    for (int m = 0; m < 4; ++m)
#pragma unroll
      for (int n = 0; n < 2; ++n)
#pragma unroll
        for (int ks = 0; ks < 2; ++ks)
          acc[m + 4][n + 2] = __builtin_amdgcn_mfma_f32_16x16x32_bf16(
              aHi[m][ks], bHi[n][ks], acc[m + 4][n + 2], 0, 0, 0);
#pragma unroll
    for (int m = 0; m < 4; ++m)
#pragma unroll
      for (int n = 0; n < 2; ++n)
#pragma unroll
        for (int ks = 0; ks < 2; ++ks)
          acc[m + 4][n] = __builtin_amdgcn_mfma_f32_16x16x32_bf16(
              aHi[m][ks], bLo[n][ks], acc[m + 4][n], 0, 0, 0);
    __builtin_amdgcn_s_setprio(0);
  }
}

// ---------------- batched gate GEMM: z = {f, o, i_raw, z_raw} ----------------
struct GateArgs {
  const unsigned short* A[4];
  const unsigned short* W[4];
  const float* bias[4];
  unsigned short* out[4];
};

__global__ __launch_bounds__(512, 2) void gemm_gates8(GateArgs ga) {
  extern __shared__ char lds[];
  const int tid = threadIdx.x;
  const int wave = tid >> 6, lane = tid & 63;
  const int bm = blockIdx.x, bn = blockIdx.y, gz = blockIdx.z;
  const int wm = (wave >> 2) * 128, wn = (wave & 3) * 64;
  const int lrow = lane & 15, lgrp = lane >> 4;

  f32x4 acc[8][4];
#pragma unroll
  for (int m = 0; m < 8; ++m)
#pragma unroll
    for (int n = 0; n < 4; ++n) acc[m][n] = (f32x4){0.f, 0.f, 0.f, 0.f};

  gemm256_core(ga.A[gz], ga.W[gz], lds, tid, wave, lane, bm, bn, acc);

  const float* bias = ga.bias[gz];
  unsigned short* out = ga.out[gz];
  float bv[4];
#pragma unroll
  for (int n = 0; n < 4; ++n) bv[n] = bias[bn * 256 + wn + n * 16 + lrow];

#pragma unroll
  for (int m = 0; m < 8; ++m)
#pragma unroll
    for (int n = 0; n < 4; ++n) {
      const int gc = bn * 256 + wn + n * 16 + lrow;
#pragma unroll
      for (int j = 0; j < 4; ++j) {
        const int gr = bm * 256 + wm + m * 16 + lgrp * 4 + j;
        float v = acc[m][n][j] + bv[n];
        if (gz == 0) v = sigmoidf_(v + 1.0f);       // f gate
        else if (gz == 1) v = sigmoidf_(v);         // o gate
        // gz==2 (i) / gz==3 (z): raw pre-activation (bias included)
        out[(size_t)gr * GN + gc] = f2bf(v);
      }
    }
}

// ---------------- output projection: bf16 A (Hb), f32 out ----------------
__global__ __launch_bounds__(512, 2) void gemm_proj8(
    const unsigned short* __restrict__ A, const unsigned short* __restrict__ W,
    const float* __restrict__ bias, float* __restrict__ out) {
  extern __shared__ char lds[];
  const int tid = threadIdx.x;
  const int wave = tid >> 6, lane = tid & 63;
  const int bm = blockIdx.x, bn = blockIdx.y;
  const int wm = (wave >> 2) * 128, wn = (wave & 3) * 64;
  const int lrow = lane & 15, lgrp = lane >> 4;

  f32x4 acc[8][4];
#pragma unroll
  for (int m = 0; m < 8; ++m)
#pragma unroll
    for (int n = 0; n < 4; ++n) acc[m][n] = (f32x4){0.f, 0.f, 0.f, 0.f};

  gemm256_core(A, W, lds, tid, wave, lane, bm, bn, acc);

  float bv[4];
#pragma unroll
  for (int n = 0; n < 4; ++n) bv[n] = bias[bn * 256 + wn + n * 16 + lrow];

#pragma unroll
  for (int m = 0; m < 8; ++m)
#pragma unroll
    for (int n = 0; n < 4; ++n) {
      const int gc = bn * 256 + wn + n * 16 + lrow;
#pragma unroll
      for (int j = 0; j < 4; ++j) {
        const int gr = bm * 256 + wm + m * 16 + lgrp * 4 + j;
        out[(size_t)gr * GN + gc] = acc[m][n][j] + bv[n];
      }
    }
}

// ---------------- scan phase A: per-chunk (prod f, local c) ----------------
__global__ void scan_phaseA_kernel(const unsigned short* __restrict__ F,
                                   const unsigned short* __restrict__ Ip,
                                   const unsigned short* __restrict__ Zp,
                                   float* __restrict__ Pt, float* __restrict__ Ct) {
  int tid = blockIdx.x * blockDim.x + threadIdx.x;  // NCH * NCHUNK = 262144
  int ch = tid & (NCH - 1), chunk = tid >> 12;
  int b = ch >> 10, n = ch & 1023;
  size_t base = ((size_t)(b * 2048 + chunk * CHUNK)) * 1024 + n;
  float c = 0.f, P = 1.f;
#pragma unroll 8
  for (int t = 0; t < CHUNK; ++t) {
    size_t idx = base + (size_t)t * 1024;
    float f = bf2f(F[idx]);
    float u = sigmoidf_(bf2f(Ip[idx])) * tanhf(bf2f(Zp[idx]));
    c = __builtin_fmaf(f, c, u);
    P *= f;
  }
  Pt[tid] = P;
  Ct[tid] = c;
}

// ---------------- scan combine: sequential over 64 chunks ----------------
__global__ void scan_combine_kernel(const float* __restrict__ Pt,
                                    const float* __restrict__ Ct,
                                    const float* __restrict__ c0,
                                    float* __restrict__ Cin,
                                    float* __restrict__ last_c) {
  int ch = blockIdx.x * blockDim.x + threadIdx.x;  // 4096
  float c = c0[ch];
#pragma unroll
  for (int j = 0; j < NCHUNK; ++j) {
    Cin[j * NCH + ch] = c;
    c = __builtin_fmaf(Pt[j * NCH + ch], c, Ct[j * NCH + ch]);
  }
  last_c[ch] = c;
}

// ---------------- scan phase C: replay with carry, emit h ----------------
__global__ void scan_phaseC_kernel(const unsigned short* __restrict__ F,
                                   const unsigned short* __restrict__ Ip,
                                   const unsigned short* __restrict__ Zp,
                                   const unsigned short* __restrict__ O,
                                   const float* __restrict__ Cin,
                                   unsigned short* __restrict__ Hb,
                                   float* __restrict__ last_h) {
  int tid = blockIdx.x * blockDim.x + threadIdx.x;
  int ch = tid & (NCH - 1), chunk = tid >> 12;
  int b = ch >> 10, n = ch & 1023;
  size_t base = ((size_t)(b * 2048 + chunk * CHUNK)) * 1024 + n;
  float c = Cin[tid];  // tid == chunk*NCH + ch
  float h = 0.f;
#pragma unroll 8
  for (int t = 0; t < CHUNK; ++t) {
    size_t idx = base + (size_t)t * 1024;
    float f = bf2f(F[idx]);
    float u = sigmoidf_(bf2f(Ip[idx])) * tanhf(bf2f(Zp[idx]));
    float o = bf2f(O[idx]);
    c = __builtin_fmaf(f, c, u);
    h = o * tanhf(c);
    Hb[idx] = f2bf(h);
  }
  if (chunk == NCHUNK - 1) last_h[ch] = h;
}

extern "C" void kernel_launch(void* const* d_in, const int* in_sizes, int n_in,
                              void* d_out, int out_size, void* d_ws, size_t ws_size,
                              hipStream_t stream) {
  const float* f_in = (const float*)d_in[0];
  const float* i_in = (const float*)d_in[1];
  const float* z_in = (const float*)d_in[2];
  const float* o_in = (const float*)d_in[3];
  const float* c0 = (const float*)d_in[4];
  // d_in[5] = h0 (unused by reference)
  const float* Wf = (const float*)d_in[6];
  const float* bf_ = (const float*)d_in[7];
  const float* Wi = (const float*)d_in[8];
  const float* bi = (const float*)d_in[9];
  const float* Wz = (const float*)d_in[10];
  const float* bz = (const float*)d_in[11];
  const float* Wo = (const float*)d_in[12];
  const float* bo = (const float*)d_in[13];
  const float* Wp = (const float*)d_in[14];
  const float* bp = (const float*)d_in[15];

  float* y = (float*)d_out;
  float* last_c = y + NACT;
  float* last_h = last_c + NCH;

  // workspace carve (Hb aliases Af, which is dead after gate GEMMs)
  char* w = (char*)d_ws;
  const size_t ABYTES = NACT * 2;             // 16 MiB
  const size_t WBYTES = (size_t)GK * GN * 2;  // 2 MiB
  unsigned short* Af = (unsigned short*)(w + 0 * ABYTES);
  unsigned short* Ai = (unsigned short*)(w + 1 * ABYTES);
  unsigned short* Az = (unsigned short*)(w + 2 * ABYTES);
  unsigned short* Ao = (unsigned short*)(w + 3 * ABYTES);
  char* wt = w + 4 * ABYTES;
  unsigned short* Wtf = (unsigned short*)(wt + 0 * WBYTES);
  unsigned short* Wti = (unsigned short*)(wt + 1 * WBYTES);
  unsigned short* Wtz = (unsigned short*)(wt + 2 * WBYTES);
  unsigned short* Wto = (unsigned short*)(wt + 3 * WBYTES);
  unsigned short* Wtp = (unsigned short*)(wt + 4 * WBYTES);
  char* gp = wt + 5 * WBYTES;
  unsigned short* F = (unsigned short*)(gp + 0 * ABYTES);
  unsigned short* O = (unsigned short*)(gp + 1 * ABYTES);
  unsigned short* Ip = (unsigned short*)(gp + 2 * ABYTES);
  unsigned short* Zp = (unsigned short*)(gp + 3 * ABYTES);
  unsigned short* Hb = Af;  // alias: Af no longer needed after gate GEMMs
  char* sp = gp + 4 * ABYTES;
  const size_t SBYTES = (size_t)NCH * NCHUNK * 4;  // 1 MiB
  float* Pt = (float*)(sp + 0 * SBYTES);
  float* Ct = (float*)(sp + 1 * SBYTES);
  float* Cin = (float*)(sp + 2 * SBYTES);

  // allow 128 KiB dynamic LDS for the GEMM kernels (idempotent, capture-safe)
  (void)hipFuncSetAttribute((const void*)gemm_gates8,
                            hipFuncAttributeMaxDynamicSharedMemorySize, 131072);
  (void)hipFuncSetAttribute((const void*)gemm_proj8,
                            hipFuncAttributeMaxDynamicSharedMemorySize, 131072);

  // 1) convert activations f32 -> bf16 (one dispatch)
  cvt4_kernel<<<dim3(1024, 4), 256, 0, stream>>>(
      f_in, o_in, i_in, z_in, Af, Ao, Ai, Az, (int)(NACT / 4));

  // 2) transpose+convert weights -> Wt[n][k] bf16 (one dispatch)
  TPtrs tp;
  tp.src[0] = Wf; tp.src[1] = Wi; tp.src[2] = Wz; tp.src[3] = Wo; tp.src[4] = Wp;
  tp.dst[0] = Wtf; tp.dst[1] = Wti; tp.dst[2] = Wtz; tp.dst[3] = Wto; tp.dst[4] = Wtp;
  transpose_cvt_all<<<dim3(32, 32, 5), 256, 0, stream>>>(tp);

  // 3) all 4 gate GEMMs in one dispatch (512 blocks = 2 full CU rounds)
  GateArgs ga;
  ga.A[0] = Af;  ga.A[1] = Ao;  ga.A[2] = Ai;  ga.A[3] = Az;
  ga.W[0] = Wtf; ga.W[1] = Wto; ga.W[2] = Wti; ga.W[3] = Wtz;
  ga.bias[0] = bf_; ga.bias[1] = bo; ga.bias[2] = bi; ga.bias[3] = bz;
  ga.out[0] = F; ga.out[1] = O; ga.out[2] = Ip; ga.out[3] = Zp;
  gemm_gates8<<<dim3(GM / 256, GN / 256, 4), 512, 131072, stream>>>(ga);

  // 4) chunked linear-recurrence scan (u = sigmoid(ip)*tanh(zp) computed in-scan)
  scan_phaseA_kernel<<<(NCH * NCHUNK) / 256, 256, 0, stream>>>(F, Ip, Zp, Pt, Ct);
  scan_combine_kernel<<<NCH / 256, 256, 0, stream>>>(Pt, Ct, c0, Cin, last_c);
  scan_phaseC_kernel<<<(NCH * NCHUNK) / 256, 256, 0, stream>>>(F, Ip, Zp, O, Cin, Hb,
                                                               last_h);

  // 5) output projection
  gemm_proj8<<<dim3(GM / 256, GN / 256), 512, 131072, stream>>>(Hb, Wtp, bp, y);
}